// Round 9
// baseline (1050.165 us; speedup 1.0000x reference)
//
#include <hip/hip_runtime.h>
#include <hip/hip_bf16.h>
#include <stdint.h>

#define BB    4
#define NQ    8192
#define NS    4096
#define FDIM  256
#define KNN   8
#define QPB   16                 // queries per block
#define CAP   128                // candidate capacity per query (E[cnt]=64)
#define MARGIN 0.0035f           // > 2x bf16-split error bound (~1.1e-3)
#define NSQ   (NS / 4)           // sensors per wave quarter = 1024
#define QTILES (NSQ / 16)        // 64 MFMA tiles per quarter
#define SSTRIDE 8                // sample every 8th tile (512 sensors/query)

typedef unsigned long long u64;
typedef __attribute__((ext_vector_type(8))) short bf16x8;   // 8 bf16 (4 VGPR)
typedef __attribute__((ext_vector_type(4))) float f32x4;

__device__ __forceinline__ float med3(float a, float b, float c) {
    return __builtin_amdgcn_fmed3f(a, b, c);
}
__device__ __forceinline__ unsigned short f2bf(float v) {
    __hip_bfloat16 h = __float2bfloat16(v);
    return *reinterpret_cast<unsigned short*>(&h);
}
__device__ __forceinline__ float bf2f(unsigned short u) {
    __hip_bfloat16 h;
    *reinterpret_cast<unsigned short*>(&h) = u;
    return __bfloat162float(h);
}

// ============ build: per-sensor K-vector table [NS][16] bf16 (128 KB) ============
// k: 0:s2_hi 1:s2_lo 2:mx_hi 3:mx_lo 4:mx_hi 5:my_hi 6:my_lo 7:my_hi
//    8:mz_hi 9:mz_lo 10:mz_hi 11..15:0        (m* = -2*coord)   [layout verified r8]
__global__ __launch_bounds__(256) void build_tbl(const float* __restrict__ sc,
                                                 unsigned short* __restrict__ tbl) {
    const int s = blockIdx.x * 256 + threadIdx.x;
    if (s >= NS) return;
    const float sx = sc[3*s], sy = sc[3*s+1], sz = sc[3*s+2];
    const float s2 = __fmaf_rn(sx, sx, __fmaf_rn(sy, sy, __fmul_rn(sz, sz)));
    const float mx = -2.0f*sx, my = -2.0f*sy, mz = -2.0f*sz;
    unsigned short e[16];
    #pragma unroll
    for (int j = 0; j < 16; ++j) e[j] = 0;
    unsigned short h, l;
    h = f2bf(s2); l = f2bf(s2 - bf2f(h)); e[0] = h; e[1] = l;
    h = f2bf(mx); l = f2bf(mx - bf2f(h)); e[2] = h; e[3] = l; e[4]  = h;
    h = f2bf(my); l = f2bf(my - bf2f(h)); e[5] = h; e[6] = l; e[7]  = h;
    h = f2bf(mz); l = f2bf(mz - bf2f(h)); e[8] = h; e[9] = l; e[10] = h;
    #pragma unroll
    for (int j = 0; j < 16; ++j) tbl[s * 16 + j] = e[j];
}

// ============ main: sampled threshold -> MFMA membership sweep -> exact refine ======
__global__ __launch_bounds__(256, 8) void knn_mfma(
    const float* __restrict__ qc, const float* __restrict__ sc,
    const float* __restrict__ sf, const unsigned short* __restrict__ tbl,
    float* __restrict__ out)
{
    __shared__ unsigned short s_qvec[QPB][32];   // query K-vectors (k11..31 zero)
    __shared__ float4 s_q[QPB];                  // qx,qy,qz,q2 (f32, refine)
    __shared__ float  s_thr[QPB][4];
    __shared__ int    s_cnt[QPB];
    __shared__ int    s_cand[QPB][CAP];          // 8 KB
    __shared__ int    s_idx[QPB][KNN];
    __shared__ float  s_w[QPB][KNN];

    const int tid = threadIdx.x;

    // XCD swizzle: batch b -> XCD pair {2b,2b+1}; bijective over 2048 blocks.
    const int p   = blockIdx.x;
    const int b   = (p >> 1) & 3;
    const int sub = ((p >> 3) << 1) | (p & 1);   // 0..511
    const int q0  = b * NQ + sub * QPB;

    // ---- stage query K-vectors + f32 coords ----
    if (tid < QPB) {
        const float* qp = qc + (size_t)(q0 + tid) * 3;
        const float qx = qp[0], qy = qp[1], qz = qp[2];
        const float q2 = __fmaf_rn(qx, qx, __fmaf_rn(qy, qy, __fmul_rn(qz, qz)));
        s_q[tid] = make_float4(qx, qy, qz, q2);
        #pragma unroll
        for (int j = 11; j < 32; ++j) s_qvec[tid][j] = 0;
        const unsigned short one = f2bf(1.0f);
        unsigned short h, l;
        s_qvec[tid][0] = one; s_qvec[tid][1] = one;
        h = f2bf(qx); l = f2bf(qx - bf2f(h));
        s_qvec[tid][2] = h; s_qvec[tid][3] = h; s_qvec[tid][4]  = l;
        h = f2bf(qy); l = f2bf(qy - bf2f(h));
        s_qvec[tid][5] = h; s_qvec[tid][6] = h; s_qvec[tid][7]  = l;
        h = f2bf(qz); l = f2bf(qz - bf2f(h));
        s_qvec[tid][8] = h; s_qvec[tid][9] = h; s_qvec[tid][10] = l;
        s_cnt[tid] = 0;
    }
    __syncthreads();

    const int wid  = tid >> 6;        // wave = sensor quarter 0..3
    const int lane = tid & 63;
    const int kc   = lane >> 4;       // k-chunk 0..3
    const int qn   = lane & 15;       // query col within tile (== query id)
    const int sbase = wid * NSQ;

    // B fragment: col = lane&15 (query), k = 8*(lane>>4)+i  [verified r8]
    const bf16x8 bfrag = *reinterpret_cast<const bf16x8*>(&s_qvec[qn][kc * 8]);
    const f32x4 zero = {0.f, 0.f, 0.f, 0.f};

    // A fragment source: row = lane&15 (sensor in tile); k-chunks 0..1 real
    const unsigned short* abase =
        tbl + ((size_t)(sbase + qn) * 16 + (kc & 1) * 8);

    // ---- pass S: per-lane top-8 over SAMPLED tiles (every 8th) ----
    float kd[KNN];
    #pragma unroll
    for (int j = 0; j < KNN; ++j) kd[j] = 3.4e38f;

    #pragma unroll 2
    for (int ts = 0; ts < QTILES / SSTRIDE; ++ts) {   // 8 tiles
        const int t = ts * SSTRIDE;
        bf16x8 a = {};
        if (kc < 2) a = *reinterpret_cast<const bf16x8*>(abase + t * 256);
        const f32x4 d = __builtin_amdgcn_mfma_f32_16x16x32_bf16(a, bfrag, zero, 0, 0, 0);
        #pragma unroll
        for (int r = 0; r < 4; ++r) {
            const float x = d[r];
            const float nk0 = fminf(kd[0], x);
            #pragma unroll
            for (int j = KNN - 1; j >= 1; --j) kd[j] = med3(kd[j-1], kd[j], x);
            kd[0] = nk0;
        }
    }

    // ---- tournament over 4 k-lanes (xor 16,32): sample-8th of this quarter ----
    float th = 3.4e38f;
    #pragma unroll
    for (int r = 0; r < KNN; ++r) {
        float m = kd[0];
        m = fminf(m, __shfl_xor(m, 16, 64));
        m = fminf(m, __shfl_xor(m, 32, 64));
        const bool pop = (kd[0] == m);   // tie over-pop only RAISES th (safe)
        #pragma unroll
        for (int j = 0; j < KNN - 1; ++j) kd[j] = pop ? kd[j+1] : kd[j];
        kd[KNN-1] = pop ? 3.4e38f : kd[KNN-1];
        th = m;
    }
    if (lane < 16) s_thr[qn][wid] = th;
    __syncthreads();

    // any subset's 8th-smallest >= global 8th -> min over quarters valid;
    // MARGIN covers bf16-vs-exact ordering slack (superset proof as r8).
    const float thr_eff =
        fminf(fminf(s_thr[qn][0], s_thr[qn][1]),
              fminf(s_thr[qn][2], s_thr[qn][3])) + MARGIN;

    // ---- pass C: full MFMA sweep, collect candidate ids ----
    #pragma unroll 2
    for (int t = 0; t < QTILES; ++t) {
        bf16x8 a = {};
        if (kc < 2) a = *reinterpret_cast<const bf16x8*>(abase + t * 256);
        const f32x4 d = __builtin_amdgcn_mfma_f32_16x16x32_bf16(a, bfrag, zero, 0, 0, 0);
        const bool h0 = d[0] <= thr_eff, h1 = d[1] <= thr_eff;
        const bool h2 = d[2] <= thr_eff, h3 = d[3] <= thr_eff;
        if (h0 | h1 | h2 | h3) {
            #pragma unroll
            for (int r = 0; r < 4; ++r) {
                if ((r == 0 ? h0 : r == 1 ? h1 : r == 2 ? h2 : h3)) {
                    const int sid = sbase + t * 16 + kc * 4 + r;
                    const int pos = atomicAdd(&s_cnt[qn], 1);
                    if (pos < CAP) s_cand[qn][pos] = sid;
                }
            }
        }
    }
    __syncthreads();

    // ---- exact f32 refine (same arithmetic as r3-r8) + weights ----
    if (tid < QPB) {
        const float qx = s_q[tid].x, qy = s_q[tid].y, qz = s_q[tid].z, q2 = s_q[tid].w;
        const int cnt = s_cnt[tid];
        u64 best[KNN];
        #pragma unroll
        for (int j = 0; j < KNN; ++j) best[j] = ~0ull;
        if (cnt <= CAP) {
            for (int i = 0; i < cnt; ++i) {
                const int sid = s_cand[tid][i];
                const float sx = sc[3*sid], sy = sc[3*sid+1], sz = sc[3*sid+2];
                const float s2 = __fmaf_rn(sx, sx, __fmaf_rn(sy, sy, __fmul_rn(sz, sz)));
                const float x  = __fmaf_rn(qx, -2.0f*sx,
                                 __fmaf_rn(qy, -2.0f*sy,
                                 __fmaf_rn(qz, -2.0f*sz, s2)));
                const float d2 = fmaxf(__fadd_rn(x, q2), 0.0f);
                u64 cur = ((u64)__float_as_uint(d2) << 32) | (unsigned)sid;
                #pragma unroll
                for (int j = 0; j < KNN; ++j) {
                    const u64 lo = best[j] < cur ? best[j] : cur;
                    const u64 hi = best[j] < cur ? cur : best[j];
                    best[j] = lo; cur = hi;
                }
            }
        } else {
            // safety net (prob ~0): exact serial full scan, still deterministic
            for (int sid = 0; sid < NS; ++sid) {
                const float sx = sc[3*sid], sy = sc[3*sid+1], sz = sc[3*sid+2];
                const float s2 = __fmaf_rn(sx, sx, __fmaf_rn(sy, sy, __fmul_rn(sz, sz)));
                const float x  = __fmaf_rn(qx, -2.0f*sx,
                                 __fmaf_rn(qy, -2.0f*sy,
                                 __fmaf_rn(qz, -2.0f*sz, s2)));
                const float d2 = fmaxf(__fadd_rn(x, q2), 0.0f);
                u64 cur = ((u64)__float_as_uint(d2) << 32) | (unsigned)sid;
                #pragma unroll
                for (int j = 0; j < KNN; ++j) {
                    const u64 lo = best[j] < cur ? best[j] : cur;
                    const u64 hi = best[j] < cur ? cur : best[j];
                    best[j] = lo; cur = hi;
                }
            }
        }
        float wv[KNN]; float wsum = 0.0f;
        #pragma unroll
        for (int j = 0; j < KNN; ++j) {
            const float d2v = __uint_as_float((unsigned)(best[j] >> 32));
            wv[j] = 1.0f / (sqrtf(d2v) + 1e-8f);
            wsum += wv[j];
            s_idx[tid][j] = (int)(unsigned)(best[j] & 0xFFFFFFFFu);
        }
        #pragma unroll
        for (int j = 0; j < KNN; ++j) s_w[tid][j] = wv[j] / wsum;
    }
    __syncthreads();

    // ---- gather: wave wid -> queries wid*4..+3; 64 lanes x float4 ----
    const float* fb = sf + (size_t)b * NS * FDIM;
    #pragma unroll 1
    for (int jq = 0; jq < QPB / 4; ++jq) {
        const int ql = wid * (QPB / 4) + jq;
        float4 acc = {0.f, 0.f, 0.f, 0.f};
        #pragma unroll
        for (int kk = 0; kk < KNN; ++kk) {
            const int   sid = s_idx[ql][kk];
            const float wk  = s_w[ql][kk];
            const float4 v = ((const float4*)(fb + (size_t)sid * FDIM))[lane];
            acc.x += wk * v.x; acc.y += wk * v.y;
            acc.z += wk * v.z; acc.w += wk * v.w;
        }
        ((float4*)(out + (size_t)(q0 + ql) * FDIM))[lane] = acc;
    }
}

// ================= fallback (round-6 kernel) if workspace too small =================
#define FG    16
#define FQL   2
#define FNT   512
#define FGRP  (FNT / FG)
#define FQPB  (FGRP * FQL)
#define FSCAN (NS / FG)
#define FCAP  16

#define FKEYX(m, qq) __fmaf_rn(fqx[qq], (m).x, \
                     __fmaf_rn(fqy[qq], (m).y, \
                     __fmaf_rn(fqz[qq], (m).z, (m).w)))

__global__ __launch_bounds__(FNT, 4) void idw_fallback(
    const float* __restrict__ qc, const float* __restrict__ sc,
    const float* __restrict__ sf, float* __restrict__ out)
{
    __shared__ float4 s_m[NS];
    __shared__ u64    s_items[FQPB * FCAP];
    __shared__ int    s_cnt[FQPB];
    __shared__ int    s_idx[FQPB * KNN];
    __shared__ float  s_w[FQPB * KNN];

    const int tid = threadIdx.x;
    const int p   = blockIdx.x;
    const int b   = (p >> 1) & 3;
    const int sub = ((p >> 3) << 1) | (p & 1);
    const int q0  = b * NQ + sub * FQPB;

    for (int s = tid; s < NS; s += FNT) {
        const float sx = sc[3*s+0], sy = sc[3*s+1], sz = sc[3*s+2];
        const float s2 = __fmaf_rn(sx, sx, __fmaf_rn(sy, sy, __fmul_rn(sz, sz)));
        s_m[s] = make_float4(-2.0f*sx, -2.0f*sy, -2.0f*sz, s2);
    }
    if (tid < FQPB) s_cnt[tid] = 0;
    __syncthreads();

    const int g = tid >> 4, l = tid & 15;
    float fqx[FQL], fqy[FQL], fqz[FQL], fq2[FQL];
    #pragma unroll
    for (int qq = 0; qq < FQL; ++qq) {
        const float* qp = qc + (size_t)(q0 + g * FQL + qq) * 3;
        fqx[qq] = qp[0]; fqy[qq] = qp[1]; fqz[qq] = qp[2];
        fq2[qq] = __fmaf_rn(fqx[qq], fqx[qq],
                  __fmaf_rn(fqy[qq], fqy[qq], __fmul_rn(fqz[qq], fqz[qq])));
    }

    float kd[FQL][KNN];
    #pragma unroll
    for (int qq = 0; qq < FQL; ++qq)
        #pragma unroll
        for (int j = 0; j < KNN; ++j) kd[qq][j] = 3.4e38f;

    #pragma unroll 2
    for (int t = 0; t < FSCAN; ++t) {
        const float4 m = s_m[t * FG + l];
        #pragma unroll
        for (int qq = 0; qq < FQL; ++qq) {
            const float x = FKEYX(m, qq);
            const float nk0 = fminf(kd[qq][0], x);
            #pragma unroll
            for (int j = KNN - 1; j >= 1; --j)
                kd[qq][j] = med3(kd[qq][j-1], kd[qq][j], x);
            kd[qq][0] = nk0;
        }
    }

    float thr[FQL];
    #pragma unroll
    for (int qq = 0; qq < FQL; ++qq) {
        float thv = 3.4e38f;
        #pragma unroll
        for (int r = 0; r < KNN; ++r) {
            float m = kd[qq][0];
            m = fminf(m, __shfl_xor(m, 1, 64));
            m = fminf(m, __shfl_xor(m, 2, 64));
            m = fminf(m, __shfl_xor(m, 4, 64));
            m = fminf(m, __shfl_xor(m, 8, 64));
            const bool pop = (kd[qq][0] == m);
            #pragma unroll
            for (int j = 0; j < KNN - 1; ++j) kd[qq][j] = pop ? kd[qq][j+1] : kd[qq][j];
            kd[qq][KNN-1] = pop ? 3.4e38f : kd[qq][KNN-1];
            thv = m;
        }
        thr[qq] = thv;
    }

    #pragma unroll 2
    for (int t = 0; t < FSCAN; ++t) {
        const int s = t * FG + l;
        const float4 m = s_m[s];
        #pragma unroll
        for (int qq = 0; qq < FQL; ++qq) {
            const float x = FKEYX(m, qq);
            if (x <= thr[qq]) {
                const float dc = fmaxf(__fadd_rn(x, fq2[qq]), 0.0f);
                const u64 key = ((u64)__float_as_uint(dc) << 32) | (unsigned)s;
                const int qid = g * FQL + qq;
                const int pos = atomicAdd(&s_cnt[qid], 1);
                if (pos < FCAP) s_items[qid * FCAP + pos] = key;
            }
        }
    }
    __syncthreads();

    if (l < FQL) {
        const int qid = g * FQL + l;
        int cnt = s_cnt[qid];
        if (cnt > KNN) {
            cnt = cnt < FCAP ? cnt : FCAP;
            u64 best[KNN];
            #pragma unroll
            for (int j = 0; j < KNN; ++j) best[j] = ~0ull;
            for (int i = 0; i < cnt; ++i) {
                u64 cur = s_items[qid * FCAP + i];
                #pragma unroll
                for (int j = 0; j < KNN; ++j) {
                    const u64 lo = best[j] < cur ? best[j] : cur;
                    const u64 hi = best[j] < cur ? cur : best[j];
                    best[j] = lo; cur = hi;
                }
            }
            #pragma unroll
            for (int j = 0; j < KNN; ++j) s_items[qid * FCAP + j] = best[j];
        }
    }
    __syncthreads();

    {
        const int qq  = l >> 3;
        const int k   = l & 7;
        const int qid = g * FQL + qq;
        const u64 key = s_items[qid * FCAP + k];
        const float d2v = __uint_as_float((unsigned)(key >> 32));
        const int   idx = (int)(unsigned)(key & 0xFFFFFFFFu);
        const float w   = 1.0f / (sqrtf(d2v) + 1e-8f);
        float ws = w;
        ws += __shfl_xor(ws, 1, 64);
        ws += __shfl_xor(ws, 2, 64);
        ws += __shfl_xor(ws, 4, 64);
        s_idx[qid * KNN + k] = idx;
        s_w  [qid * KNN + k] = w / ws;
    }
    __syncthreads();

    const int wave = tid >> 6, lane = tid & 63;
    const float* fb = sf + (size_t)b * NS * FDIM;
    #pragma unroll 1
    for (int j = 0; j < FQPB / 8; ++j) {
        const int ql = wave * (FQPB / 8) + j;
        float4 acc = {0.f, 0.f, 0.f, 0.f};
        #pragma unroll
        for (int kk = 0; kk < KNN; ++kk) {
            const int   sid = s_idx[ql * KNN + kk];
            const float wk  = s_w  [ql * KNN + kk];
            const float4 v = ((const float4*)(fb + (size_t)sid * FDIM))[lane];
            acc.x += wk * v.x; acc.y += wk * v.y;
            acc.z += wk * v.z; acc.w += wk * v.w;
        }
        ((float4*)(out + (size_t)(q0 + ql) * FDIM))[lane] = acc;
    }
}

extern "C" void kernel_launch(void* const* d_in, const int* in_sizes, int n_in,
                              void* d_out, int out_size, void* d_ws, size_t ws_size,
                              hipStream_t stream) {
    const float* qc = (const float*)d_in[0];   // query_coords  (4,8192,3)
    const float* sc = (const float*)d_in[1];   // sensor_coords (4096,3)
    const float* sf = (const float*)d_in[2];   // sensor_features (4,4096,256)
    float* out = (float*)d_out;                // (4,8192,256)

    const size_t tbl_bytes = (size_t)NS * 16 * sizeof(unsigned short);  // 128 KB
    if (ws_size >= tbl_bytes) {
        unsigned short* tbl = (unsigned short*)d_ws;
        build_tbl<<<NS / 256, 256, 0, stream>>>(sc, tbl);
        knn_mfma<<<(BB * NQ) / QPB, 256, 0, stream>>>(qc, sc, sf, tbl, out);
    } else {
        idw_fallback<<<(BB * NQ) / FQPB, FNT, 0, stream>>>(qc, sc, sf, out);
    }
}

// Round 10
// 102.402 us; speedup vs baseline: 10.2553x; 10.2553x over previous
//
#include <hip/hip_runtime.h>
#include <hip/hip_bf16.h>
#include <stdint.h>

#define BB    4
#define NQ    8192
#define NS    4096
#define FDIM  256
#define KNN   8
#define QPB   16                 // queries per block
#define CAP   192                // candidate capacity (E=64, sigma~21 -> 6 sigma)
#define MARGIN 0.0035f           // > 2x bf16-split error bound (~1.1e-3)
#define NSQ   (NS / 4)           // sensors per wave quarter = 1024
#define QTILES (NSQ / 16)        // 64 MFMA tiles per quarter
#define SSTRIDE 8                // sample every 8th tile (512 sensors pooled)

typedef unsigned long long u64;
typedef __attribute__((ext_vector_type(8))) short bf16x8;   // 8 bf16 (4 VGPR)
typedef __attribute__((ext_vector_type(4))) float f32x4;

__device__ __forceinline__ float med3(float a, float b, float c) {
    return __builtin_amdgcn_fmed3f(a, b, c);
}
__device__ __forceinline__ unsigned short f2bf(float v) {
    __hip_bfloat16 h = __float2bfloat16(v);
    return *reinterpret_cast<unsigned short*>(&h);
}
__device__ __forceinline__ float bf2f(unsigned short u) {
    __hip_bfloat16 h;
    *reinterpret_cast<unsigned short*>(&h) = u;
    return __bfloat162float(h);
}

// ============ build: per-sensor K-vector table [NS][16] bf16 (128 KB) ============
// k: 0:s2_hi 1:s2_lo 2:mx_hi 3:mx_lo 4:mx_hi 5:my_hi 6:my_lo 7:my_hi
//    8:mz_hi 9:mz_lo 10:mz_hi 11..15:0        (m* = -2*coord)   [layout verified r8]
__global__ __launch_bounds__(256) void build_tbl(const float* __restrict__ sc,
                                                 unsigned short* __restrict__ tbl) {
    const int s = blockIdx.x * 256 + threadIdx.x;
    if (s >= NS) return;
    const float sx = sc[3*s], sy = sc[3*s+1], sz = sc[3*s+2];
    const float s2 = __fmaf_rn(sx, sx, __fmaf_rn(sy, sy, __fmul_rn(sz, sz)));
    const float mx = -2.0f*sx, my = -2.0f*sy, mz = -2.0f*sz;
    unsigned short e[16];
    #pragma unroll
    for (int j = 0; j < 16; ++j) e[j] = 0;
    unsigned short h, l;
    h = f2bf(s2); l = f2bf(s2 - bf2f(h)); e[0] = h; e[1] = l;
    h = f2bf(mx); l = f2bf(mx - bf2f(h)); e[2] = h; e[3] = l; e[4]  = h;
    h = f2bf(my); l = f2bf(my - bf2f(h)); e[5] = h; e[6] = l; e[7]  = h;
    h = f2bf(mz); l = f2bf(mz - bf2f(h)); e[8] = h; e[9] = l; e[10] = h;
    #pragma unroll
    for (int j = 0; j < 16; ++j) tbl[s * 16 + j] = e[j];
}

// ===== main: pooled-sample threshold -> MFMA membership sweep -> exact refine =====
__global__ __launch_bounds__(256, 8) void knn_mfma(
    const float* __restrict__ qc, const float* __restrict__ sc,
    const float* __restrict__ sf, const unsigned short* __restrict__ tbl,
    float* __restrict__ out)
{
    __shared__ unsigned short s_qvec[QPB][32];   // query K-vectors (k11..31 zero)
    __shared__ float4 s_q[QPB];                  // qx,qy,qz,q2 (f32, refine)
    __shared__ float  s_samp[QPB][4][KNN];       // per-quarter sample-top-8 (2 KB)
    __shared__ float  s_thrq[QPB];               // pooled threshold (+MARGIN)
    __shared__ int    s_cnt[QPB];
    __shared__ int    s_cand[QPB][CAP];          // 12 KB
    __shared__ int    s_idx[QPB][KNN];
    __shared__ float  s_w[QPB][KNN];

    const int tid = threadIdx.x;

    // XCD swizzle: batch b -> XCD pair {2b,2b+1}; bijective over 2048 blocks.
    const int p   = blockIdx.x;
    const int b   = (p >> 1) & 3;
    const int sub = ((p >> 3) << 1) | (p & 1);   // 0..511
    const int q0  = b * NQ + sub * QPB;

    // ---- stage query K-vectors + f32 coords ----
    if (tid < QPB) {
        const float* qp = qc + (size_t)(q0 + tid) * 3;
        const float qx = qp[0], qy = qp[1], qz = qp[2];
        const float q2 = __fmaf_rn(qx, qx, __fmaf_rn(qy, qy, __fmul_rn(qz, qz)));
        s_q[tid] = make_float4(qx, qy, qz, q2);
        #pragma unroll
        for (int j = 11; j < 32; ++j) s_qvec[tid][j] = 0;
        const unsigned short one = f2bf(1.0f);
        unsigned short h, l;
        s_qvec[tid][0] = one; s_qvec[tid][1] = one;
        h = f2bf(qx); l = f2bf(qx - bf2f(h));
        s_qvec[tid][2] = h; s_qvec[tid][3] = h; s_qvec[tid][4]  = l;
        h = f2bf(qy); l = f2bf(qy - bf2f(h));
        s_qvec[tid][5] = h; s_qvec[tid][6] = h; s_qvec[tid][7]  = l;
        h = f2bf(qz); l = f2bf(qz - bf2f(h));
        s_qvec[tid][8] = h; s_qvec[tid][9] = h; s_qvec[tid][10] = l;
        s_cnt[tid] = 0;
    }
    __syncthreads();

    const int wid  = tid >> 6;        // wave = sensor quarter 0..3
    const int lane = tid & 63;
    const int kc   = lane >> 4;       // k-chunk 0..3
    const int qn   = lane & 15;       // query col within tile (== query id)
    const int sbase = wid * NSQ;

    // B fragment: col = lane&15 (query), k = 8*(lane>>4)+i  [verified r8]
    const bf16x8 bfrag = *reinterpret_cast<const bf16x8*>(&s_qvec[qn][kc * 8]);
    const f32x4 zero = {0.f, 0.f, 0.f, 0.f};

    // A fragment source: row = lane&15 (sensor in tile); k-chunks 0..1 real
    const unsigned short* abase =
        tbl + ((size_t)(sbase + qn) * 16 + (kc & 1) * 8);

    // ---- pass S: per-lane top-8 over SAMPLED tiles (every 8th) ----
    float kd[KNN];
    #pragma unroll
    for (int j = 0; j < KNN; ++j) kd[j] = 3.4e38f;

    #pragma unroll 2
    for (int ts = 0; ts < QTILES / SSTRIDE; ++ts) {   // 8 tiles = 128 sensors
        const int t = ts * SSTRIDE;
        bf16x8 a = {};
        if (kc < 2) a = *reinterpret_cast<const bf16x8*>(abase + t * 256);
        const f32x4 d = __builtin_amdgcn_mfma_f32_16x16x32_bf16(a, bfrag, zero, 0, 0, 0);
        #pragma unroll
        for (int r = 0; r < 4; ++r) {
            const float x = d[r];
            const float nk0 = fminf(kd[0], x);
            #pragma unroll
            for (int j = KNN - 1; j >= 1; --j) kd[j] = med3(kd[j-1], kd[j], x);
            kd[0] = nk0;
        }
    }

    // ---- tournament over 4 k-lanes: RECORD all 8 winners (quarter sample-top8).
    // Tie over-pop can only skip duplicates -> recorded values only rise -> safe.
    float smp[KNN];
    #pragma unroll
    for (int r = 0; r < KNN; ++r) {
        float m = kd[0];
        m = fminf(m, __shfl_xor(m, 16, 64));
        m = fminf(m, __shfl_xor(m, 32, 64));
        const bool pop = (kd[0] == m);
        #pragma unroll
        for (int j = 0; j < KNN - 1; ++j) kd[j] = pop ? kd[j+1] : kd[j];
        kd[KNN-1] = pop ? 3.4e38f : kd[KNN-1];
        smp[r] = m;
    }
    if (kc == 0) {
        #pragma unroll
        for (int r = 0; r < KNN; ++r) s_samp[qn][wid][r] = smp[r];
    }
    __syncthreads();

    // ---- pool the 4x8 quarter lists -> pooled sample-8th (rank ~64 of 4096) ----
    if (tid < QPB) {
        float pk[KNN];
        #pragma unroll
        for (int j = 0; j < KNN; ++j) pk[j] = 3.4e38f;
        #pragma unroll
        for (int w4 = 0; w4 < 4; ++w4) {
            #pragma unroll
            for (int r = 0; r < KNN; ++r) {
                const float x = s_samp[tid][w4][r];
                const float nk0 = fminf(pk[0], x);
                #pragma unroll
                for (int j = KNN - 1; j >= 1; --j) pk[j] = med3(pk[j-1], pk[j], x);
                pk[0] = nk0;
            }
        }
        s_thrq[tid] = pk[KNN - 1] + MARGIN;   // superset threshold (proof as r8)
    }
    __syncthreads();

    const float thr_eff = s_thrq[qn];

    // ---- pass C: full MFMA sweep, collect candidate ids ----
    #pragma unroll 2
    for (int t = 0; t < QTILES; ++t) {
        bf16x8 a = {};
        if (kc < 2) a = *reinterpret_cast<const bf16x8*>(abase + t * 256);
        const f32x4 d = __builtin_amdgcn_mfma_f32_16x16x32_bf16(a, bfrag, zero, 0, 0, 0);
        const bool h0 = d[0] <= thr_eff, h1 = d[1] <= thr_eff;
        const bool h2 = d[2] <= thr_eff, h3 = d[3] <= thr_eff;
        if (h0 | h1 | h2 | h3) {
            #pragma unroll
            for (int r = 0; r < 4; ++r) {
                if ((r == 0 ? h0 : r == 1 ? h1 : r == 2 ? h2 : h3)) {
                    const int sid = sbase + t * 16 + kc * 4 + r;
                    const int pos = atomicAdd(&s_cnt[qn], 1);
                    if (pos < CAP) s_cand[qn][pos] = sid;
                }
            }
        }
    }
    __syncthreads();

    // ---- exact f32 refine (same arithmetic as r3-r9) + weights ----
    if (tid < QPB) {
        const float qx = s_q[tid].x, qy = s_q[tid].y, qz = s_q[tid].z, q2 = s_q[tid].w;
        const int cnt = s_cnt[tid];
        u64 best[KNN];
        #pragma unroll
        for (int j = 0; j < KNN; ++j) best[j] = ~0ull;
        if (cnt <= CAP) {
            for (int i = 0; i < cnt; ++i) {
                const int sid = s_cand[tid][i];
                const float sx = sc[3*sid], sy = sc[3*sid+1], sz = sc[3*sid+2];
                const float s2 = __fmaf_rn(sx, sx, __fmaf_rn(sy, sy, __fmul_rn(sz, sz)));
                const float x  = __fmaf_rn(qx, -2.0f*sx,
                                 __fmaf_rn(qy, -2.0f*sy,
                                 __fmaf_rn(qz, -2.0f*sz, s2)));
                const float d2 = fmaxf(__fadd_rn(x, q2), 0.0f);
                u64 cur = ((u64)__float_as_uint(d2) << 32) | (unsigned)sid;
                #pragma unroll
                for (int j = 0; j < KNN; ++j) {
                    const u64 lo = best[j] < cur ? best[j] : cur;
                    const u64 hi = best[j] < cur ? cur : best[j];
                    best[j] = lo; cur = hi;
                }
            }
        } else {
            // safety net (>=6 sigma): exact serial full scan, still deterministic
            for (int sid = 0; sid < NS; ++sid) {
                const float sx = sc[3*sid], sy = sc[3*sid+1], sz = sc[3*sid+2];
                const float s2 = __fmaf_rn(sx, sx, __fmaf_rn(sy, sy, __fmul_rn(sz, sz)));
                const float x  = __fmaf_rn(qx, -2.0f*sx,
                                 __fmaf_rn(qy, -2.0f*sy,
                                 __fmaf_rn(qz, -2.0f*sz, s2)));
                const float d2 = fmaxf(__fadd_rn(x, q2), 0.0f);
                u64 cur = ((u64)__float_as_uint(d2) << 32) | (unsigned)sid;
                #pragma unroll
                for (int j = 0; j < KNN; ++j) {
                    const u64 lo = best[j] < cur ? best[j] : cur;
                    const u64 hi = best[j] < cur ? cur : best[j];
                    best[j] = lo; cur = hi;
                }
            }
        }
        float wv[KNN]; float wsum = 0.0f;
        #pragma unroll
        for (int j = 0; j < KNN; ++j) {
            const float d2v = __uint_as_float((unsigned)(best[j] >> 32));
            wv[j] = 1.0f / (sqrtf(d2v) + 1e-8f);
            wsum += wv[j];
            s_idx[tid][j] = (int)(unsigned)(best[j] & 0xFFFFFFFFu);
        }
        #pragma unroll
        for (int j = 0; j < KNN; ++j) s_w[tid][j] = wv[j] / wsum;
    }
    __syncthreads();

    // ---- gather: wave wid -> queries wid*4..+3; 64 lanes x float4 ----
    const float* fb = sf + (size_t)b * NS * FDIM;
    #pragma unroll 1
    for (int jq = 0; jq < QPB / 4; ++jq) {
        const int ql = wid * (QPB / 4) + jq;
        float4 acc = {0.f, 0.f, 0.f, 0.f};
        #pragma unroll
        for (int kk = 0; kk < KNN; ++kk) {
            const int   sid = s_idx[ql][kk];
            const float wk  = s_w[ql][kk];
            const float4 v = ((const float4*)(fb + (size_t)sid * FDIM))[lane];
            acc.x += wk * v.x; acc.y += wk * v.y;
            acc.z += wk * v.z; acc.w += wk * v.w;
        }
        ((float4*)(out + (size_t)(q0 + ql) * FDIM))[lane] = acc;
    }
}

// ================= fallback (round-6 kernel) if workspace too small =================
#define FG    16
#define FQL   2
#define FNT   512
#define FGRP  (FNT / FG)
#define FQPB  (FGRP * FQL)
#define FSCAN (NS / FG)
#define FCAP  16

#define FKEYX(m, qq) __fmaf_rn(fqx[qq], (m).x, \
                     __fmaf_rn(fqy[qq], (m).y, \
                     __fmaf_rn(fqz[qq], (m).z, (m).w)))

__global__ __launch_bounds__(FNT, 4) void idw_fallback(
    const float* __restrict__ qc, const float* __restrict__ sc,
    const float* __restrict__ sf, float* __restrict__ out)
{
    __shared__ float4 s_m[NS];
    __shared__ u64    s_items[FQPB * FCAP];
    __shared__ int    s_cnt[FQPB];
    __shared__ int    s_idx[FQPB * KNN];
    __shared__ float  s_w[FQPB * KNN];

    const int tid = threadIdx.x;
    const int p   = blockIdx.x;
    const int b   = (p >> 1) & 3;
    const int sub = ((p >> 3) << 1) | (p & 1);
    const int q0  = b * NQ + sub * FQPB;

    for (int s = tid; s < NS; s += FNT) {
        const float sx = sc[3*s+0], sy = sc[3*s+1], sz = sc[3*s+2];
        const float s2 = __fmaf_rn(sx, sx, __fmaf_rn(sy, sy, __fmul_rn(sz, sz)));
        s_m[s] = make_float4(-2.0f*sx, -2.0f*sy, -2.0f*sz, s2);
    }
    if (tid < FQPB) s_cnt[tid] = 0;
    __syncthreads();

    const int g = tid >> 4, l = tid & 15;
    float fqx[FQL], fqy[FQL], fqz[FQL], fq2[FQL];
    #pragma unroll
    for (int qq = 0; qq < FQL; ++qq) {
        const float* qp = qc + (size_t)(q0 + g * FQL + qq) * 3;
        fqx[qq] = qp[0]; fqy[qq] = qp[1]; fqz[qq] = qp[2];
        fq2[qq] = __fmaf_rn(fqx[qq], fqx[qq],
                  __fmaf_rn(fqy[qq], fqy[qq], __fmul_rn(fqz[qq], fqz[qq])));
    }

    float kd[FQL][KNN];
    #pragma unroll
    for (int qq = 0; qq < FQL; ++qq)
        #pragma unroll
        for (int j = 0; j < KNN; ++j) kd[qq][j] = 3.4e38f;

    #pragma unroll 2
    for (int t = 0; t < FSCAN; ++t) {
        const float4 m = s_m[t * FG + l];
        #pragma unroll
        for (int qq = 0; qq < FQL; ++qq) {
            const float x = FKEYX(m, qq);
            const float nk0 = fminf(kd[qq][0], x);
            #pragma unroll
            for (int j = KNN - 1; j >= 1; --j)
                kd[qq][j] = med3(kd[qq][j-1], kd[qq][j], x);
            kd[qq][0] = nk0;
        }
    }

    float thr[FQL];
    #pragma unroll
    for (int qq = 0; qq < FQL; ++qq) {
        float thv = 3.4e38f;
        #pragma unroll
        for (int r = 0; r < KNN; ++r) {
            float m = kd[qq][0];
            m = fminf(m, __shfl_xor(m, 1, 64));
            m = fminf(m, __shfl_xor(m, 2, 64));
            m = fminf(m, __shfl_xor(m, 4, 64));
            m = fminf(m, __shfl_xor(m, 8, 64));
            const bool pop = (kd[qq][0] == m);
            #pragma unroll
            for (int j = 0; j < KNN - 1; ++j) kd[qq][j] = pop ? kd[qq][j+1] : kd[qq][j];
            kd[qq][KNN-1] = pop ? 3.4e38f : kd[qq][KNN-1];
            thv = m;
        }
        thr[qq] = thv;
    }

    #pragma unroll 2
    for (int t = 0; t < FSCAN; ++t) {
        const int s = t * FG + l;
        const float4 m = s_m[s];
        #pragma unroll
        for (int qq = 0; qq < FQL; ++qq) {
            const float x = FKEYX(m, qq);
            if (x <= thr[qq]) {
                const float dc = fmaxf(__fadd_rn(x, fq2[qq]), 0.0f);
                const u64 key = ((u64)__float_as_uint(dc) << 32) | (unsigned)s;
                const int qid = g * FQL + qq;
                const int pos = atomicAdd(&s_cnt[qid], 1);
                if (pos < FCAP) s_items[qid * FCAP + pos] = key;
            }
        }
    }
    __syncthreads();

    if (l < FQL) {
        const int qid = g * FQL + l;
        int cnt = s_cnt[qid];
        if (cnt > KNN) {
            cnt = cnt < FCAP ? cnt : FCAP;
            u64 best[KNN];
            #pragma unroll
            for (int j = 0; j < KNN; ++j) best[j] = ~0ull;
            for (int i = 0; i < cnt; ++i) {
                u64 cur = s_items[qid * FCAP + i];
                #pragma unroll
                for (int j = 0; j < KNN; ++j) {
                    const u64 lo = best[j] < cur ? best[j] : cur;
                    const u64 hi = best[j] < cur ? cur : best[j];
                    best[j] = lo; cur = hi;
                }
            }
            #pragma unroll
            for (int j = 0; j < KNN; ++j) s_items[qid * FCAP + j] = best[j];
        }
    }
    __syncthreads();

    {
        const int qq  = l >> 3;
        const int k   = l & 7;
        const int qid = g * FQL + qq;
        const u64 key = s_items[qid * FCAP + k];
        const float d2v = __uint_as_float((unsigned)(key >> 32));
        const int   idx = (int)(unsigned)(key & 0xFFFFFFFFu);
        const float w   = 1.0f / (sqrtf(d2v) + 1e-8f);
        float ws = w;
        ws += __shfl_xor(ws, 1, 64);
        ws += __shfl_xor(ws, 2, 64);
        ws += __shfl_xor(ws, 4, 64);
        s_idx[qid * KNN + k] = idx;
        s_w  [qid * KNN + k] = w / ws;
    }
    __syncthreads();

    const int wave = tid >> 6, lane = tid & 63;
    const float* fb = sf + (size_t)b * NS * FDIM;
    #pragma unroll 1
    for (int j = 0; j < FQPB / 8; ++j) {
        const int ql = wave * (FQPB / 8) + j;
        float4 acc = {0.f, 0.f, 0.f, 0.f};
        #pragma unroll
        for (int kk = 0; kk < KNN; ++kk) {
            const int   sid = s_idx[ql * KNN + kk];
            const float wk  = s_w  [ql * KNN + kk];
            const float4 v = ((const float4*)(fb + (size_t)sid * FDIM))[lane];
            acc.x += wk * v.x; acc.y += wk * v.y;
            acc.z += wk * v.z; acc.w += wk * v.w;
        }
        ((float4*)(out + (size_t)(q0 + ql) * FDIM))[lane] = acc;
    }
}

extern "C" void kernel_launch(void* const* d_in, const int* in_sizes, int n_in,
                              void* d_out, int out_size, void* d_ws, size_t ws_size,
                              hipStream_t stream) {
    const float* qc = (const float*)d_in[0];   // query_coords  (4,8192,3)
    const float* sc = (const float*)d_in[1];   // sensor_coords (4096,3)
    const float* sf = (const float*)d_in[2];   // sensor_features (4,4096,256)
    float* out = (float*)d_out;                // (4,8192,256)

    const size_t tbl_bytes = (size_t)NS * 16 * sizeof(unsigned short);  // 128 KB
    if (ws_size >= tbl_bytes) {
        unsigned short* tbl = (unsigned short*)d_ws;
        build_tbl<<<NS / 256, 256, 0, stream>>>(sc, tbl);
        knn_mfma<<<(BB * NQ) / QPB, 256, 0, stream>>>(qc, sc, sf, tbl, out);
    } else {
        idw_fallback<<<(BB * NQ) / FQPB, FNT, 0, stream>>>(qc, sc, sf, out);
    }
}

// Round 11
// 75.195 us; speedup vs baseline: 13.9659x; 1.3618x over previous
//
#include <hip/hip_runtime.h>
#include <hip/hip_bf16.h>
#include <stdint.h>

#define BB    4
#define NQ    8192
#define NS    4096
#define FDIM  256
#define KNN   8
#define QPB   16                 // queries per block
#define CAP   192                // candidate capacity (E=64, sigma~23 -> 5.5 sigma)
#define MARGIN 0.0035f           // > 2x bf16-split error bound (~1.1e-3)
#define NSQ   (NS / 4)           // sensors per wave quarter = 1024
#define QTILES (NSQ / 16)        // 64 MFMA tiles per quarter
#define SSTRIDE 8                // sample every 8th tile (512 sensors pooled)

typedef unsigned long long u64;
typedef __attribute__((ext_vector_type(8))) short bf16x8;   // 8 bf16 (4 VGPR)
typedef __attribute__((ext_vector_type(4))) float f32x4;

__device__ __forceinline__ float med3(float a, float b, float c) {
    return __builtin_amdgcn_fmed3f(a, b, c);
}
__device__ __forceinline__ unsigned short f2bf(float v) {
    __hip_bfloat16 h = __float2bfloat16(v);
    return *reinterpret_cast<unsigned short*>(&h);
}
__device__ __forceinline__ float bf2f(unsigned short u) {
    __hip_bfloat16 h;
    *reinterpret_cast<unsigned short*>(&h) = u;
    return __bfloat162float(h);
}

// ---------------- d_ws layout ----------------
// tbl  : [NS][16] bf16 @ 0       (128 KB)  MFMA K-vectors [layout verified r8]
// tblf : [NS] float4  @ 131072   (64 KB)   (-2x,-2y,-2z,s^2) f32 for refine
#define WS_TBLF  131072
#define WS_NEED  196608

// ============ build: bf16 K-vector table + f32 refine table ============
// k: 0:s2_hi 1:s2_lo 2:mx_hi 3:mx_lo 4:mx_hi 5:my_hi 6:my_lo 7:my_hi
//    8:mz_hi 9:mz_lo 10:mz_hi 11..15:0        (m* = -2*coord)
__global__ __launch_bounds__(256) void build_tbl(const float* __restrict__ sc,
                                                 unsigned short* __restrict__ tbl,
                                                 float4* __restrict__ tblf) {
    const int s = blockIdx.x * 256 + threadIdx.x;
    if (s >= NS) return;
    const float sx = sc[3*s], sy = sc[3*s+1], sz = sc[3*s+2];
    const float s2 = __fmaf_rn(sx, sx, __fmaf_rn(sy, sy, __fmul_rn(sz, sz)));
    const float mx = -2.0f*sx, my = -2.0f*sy, mz = -2.0f*sz;
    unsigned short e[16];
    #pragma unroll
    for (int j = 0; j < 16; ++j) e[j] = 0;
    unsigned short h, l;
    h = f2bf(s2); l = f2bf(s2 - bf2f(h)); e[0] = h; e[1] = l;
    h = f2bf(mx); l = f2bf(mx - bf2f(h)); e[2] = h; e[3] = l; e[4]  = h;
    h = f2bf(my); l = f2bf(my - bf2f(h)); e[5] = h; e[6] = l; e[7]  = h;
    h = f2bf(mz); l = f2bf(mz - bf2f(h)); e[8] = h; e[9] = l; e[10] = h;
    #pragma unroll
    for (int j = 0; j < 16; ++j) tbl[s * 16 + j] = e[j];
    tblf[s] = make_float4(mx, my, mz, s2);
}

// ===== main: pooled-sample threshold -> MFMA sweep -> parallel exact refine =====
__global__ __launch_bounds__(256, 8) void knn_mfma(
    const float* __restrict__ qc, const float* __restrict__ sf,
    const unsigned short* __restrict__ tbl, const float4* __restrict__ tblf,
    float* __restrict__ out)
{
    __shared__ unsigned short s_qvec[QPB][32];   // query K-vectors (k11..31 zero)
    __shared__ float4 s_q[QPB];                  // qx,qy,qz,q2 (f32, refine)
    __shared__ float  s_samp[QPB][4][KNN];       // per-quarter sample-top-8
    __shared__ float  s_thrq[QPB];               // pooled threshold (+MARGIN)
    __shared__ int    s_cnt[QPB];
    __shared__ int    s_cand[QPB][CAP];          // 12 KB
    __shared__ int    s_idx[QPB][KNN];
    __shared__ float  s_w[QPB][KNN];

    const int tid = threadIdx.x;

    // XCD swizzle: batch b -> XCD pair {2b,2b+1}; bijective over 2048 blocks.
    const int p   = blockIdx.x;
    const int b   = (p >> 1) & 3;
    const int sub = ((p >> 3) << 1) | (p & 1);   // 0..511
    const int q0  = b * NQ + sub * QPB;

    // ---- stage query K-vectors + f32 coords ----
    if (tid < QPB) {
        const float* qp = qc + (size_t)(q0 + tid) * 3;
        const float qx = qp[0], qy = qp[1], qz = qp[2];
        const float q2 = __fmaf_rn(qx, qx, __fmaf_rn(qy, qy, __fmul_rn(qz, qz)));
        s_q[tid] = make_float4(qx, qy, qz, q2);
        #pragma unroll
        for (int j = 11; j < 32; ++j) s_qvec[tid][j] = 0;
        const unsigned short one = f2bf(1.0f);
        unsigned short h, l;
        s_qvec[tid][0] = one; s_qvec[tid][1] = one;
        h = f2bf(qx); l = f2bf(qx - bf2f(h));
        s_qvec[tid][2] = h; s_qvec[tid][3] = h; s_qvec[tid][4]  = l;
        h = f2bf(qy); l = f2bf(qy - bf2f(h));
        s_qvec[tid][5] = h; s_qvec[tid][6] = h; s_qvec[tid][7]  = l;
        h = f2bf(qz); l = f2bf(qz - bf2f(h));
        s_qvec[tid][8] = h; s_qvec[tid][9] = h; s_qvec[tid][10] = l;
        s_cnt[tid] = 0;
    }
    __syncthreads();

    const int wid  = tid >> 6;        // wave = sensor quarter 0..3
    const int lane = tid & 63;
    const int kc   = lane >> 4;       // k-chunk 0..3
    const int qn   = lane & 15;       // query col within tile (== query id)
    const int sbase = wid * NSQ;

    // B fragment: col = lane&15 (query), k = 8*(lane>>4)+i  [verified r8]
    const bf16x8 bfrag = *reinterpret_cast<const bf16x8*>(&s_qvec[qn][kc * 8]);
    const f32x4 zero = {0.f, 0.f, 0.f, 0.f};

    // A fragment source: row = lane&15 (sensor in tile); k-chunks 0..1 real
    const unsigned short* abase =
        tbl + ((size_t)(sbase + qn) * 16 + (kc & 1) * 8);

    // ---- pass S: per-lane top-8 over SAMPLED tiles (every 8th) ----
    float kd[KNN];
    #pragma unroll
    for (int j = 0; j < KNN; ++j) kd[j] = 3.4e38f;

    #pragma unroll 2
    for (int ts = 0; ts < QTILES / SSTRIDE; ++ts) {   // 8 tiles = 128 sensors
        const int t = ts * SSTRIDE;
        bf16x8 a = {};
        if (kc < 2) a = *reinterpret_cast<const bf16x8*>(abase + t * 256);
        const f32x4 d = __builtin_amdgcn_mfma_f32_16x16x32_bf16(a, bfrag, zero, 0, 0, 0);
        #pragma unroll
        for (int r = 0; r < 4; ++r) {
            const float x = d[r];
            const float nk0 = fminf(kd[0], x);
            #pragma unroll
            for (int j = KNN - 1; j >= 1; --j) kd[j] = med3(kd[j-1], kd[j], x);
            kd[0] = nk0;
        }
    }

    // ---- tournament over 4 k-lanes: record all 8 winners (quarter sample-top8) ----
    float smp[KNN];
    #pragma unroll
    for (int r = 0; r < KNN; ++r) {
        float m = kd[0];
        m = fminf(m, __shfl_xor(m, 16, 64));
        m = fminf(m, __shfl_xor(m, 32, 64));
        const bool pop = (kd[0] == m);   // tie over-pop only RAISES values (safe)
        #pragma unroll
        for (int j = 0; j < KNN - 1; ++j) kd[j] = pop ? kd[j+1] : kd[j];
        kd[KNN-1] = pop ? 3.4e38f : kd[KNN-1];
        smp[r] = m;
    }
    if (kc == 0) {
        #pragma unroll
        for (int r = 0; r < KNN; ++r) s_samp[qn][wid][r] = smp[r];
    }
    __syncthreads();

    // ---- pool 4x8 quarter lists -> pooled sample-8th (rank ~64 of 4096) ----
    if (tid < QPB) {
        float pk[KNN];
        #pragma unroll
        for (int j = 0; j < KNN; ++j) pk[j] = 3.4e38f;
        #pragma unroll
        for (int w4 = 0; w4 < 4; ++w4) {
            #pragma unroll
            for (int r = 0; r < KNN; ++r) {
                const float x = s_samp[tid][w4][r];
                const float nk0 = fminf(pk[0], x);
                #pragma unroll
                for (int j = KNN - 1; j >= 1; --j) pk[j] = med3(pk[j-1], pk[j], x);
                pk[0] = nk0;
            }
        }
        s_thrq[tid] = pk[KNN - 1] + MARGIN;   // superset threshold (proof as r8)
    }
    __syncthreads();

    const float thr_eff = s_thrq[qn];

    // ---- pass C: full MFMA sweep; batched-atomic candidate collection ----
    #pragma unroll 2
    for (int t = 0; t < QTILES; ++t) {
        bf16x8 a = {};
        if (kc < 2) a = *reinterpret_cast<const bf16x8*>(abase + t * 256);
        const f32x4 d = __builtin_amdgcn_mfma_f32_16x16x32_bf16(a, bfrag, zero, 0, 0, 0);
        const bool h0 = d[0] <= thr_eff, h1 = d[1] <= thr_eff;
        const bool h2 = d[2] <= thr_eff, h3 = d[3] <= thr_eff;
        const int n = (int)h0 + (int)h1 + (int)h2 + (int)h3;
        if (n) {
            int pos = atomicAdd(&s_cnt[qn], n);           // one atomic per lane
            const int sid0 = sbase + t * 16 + kc * 4;
            if (h0) { if (pos < CAP) s_cand[qn][pos] = sid0;     ++pos; }
            if (h1) { if (pos < CAP) s_cand[qn][pos] = sid0 + 1; ++pos; }
            if (h2) { if (pos < CAP) s_cand[qn][pos] = sid0 + 2; ++pos; }
            if (h3) { if (pos < CAP) s_cand[qn][pos] = sid0 + 3; }
        }
    }
    __syncthreads();

    // ---- parallel exact refine: wave wid -> queries wid*4..+3 ----
    // 16 lanes per query split candidates; per-lane sorted u64 top-8;
    // 16-lane u64 pop-tournament -> exact top-8 (keys unique -> one pop).
    {
        const int sg = lane >> 4;            // subgroup 0..3
        const int li = lane & 15;            // lane within subgroup
        const int qr = wid * 4 + sg;         // query refined by this subgroup
        const int cnt0 = s_cnt[qr];
        const float qx = s_q[qr].x, qy = s_q[qr].y, qz = s_q[qr].z, q2 = s_q[qr].w;

        u64 kb[KNN];
        #pragma unroll
        for (int j = 0; j < KNN; ++j) kb[j] = ~0ull;

        if (cnt0 <= CAP) {
            for (int i = li; i < cnt0; i += 16) {
                const int sid = s_cand[qr][i];
                const float4 m = tblf[sid];
                const float x  = __fmaf_rn(qx, m.x,
                                 __fmaf_rn(qy, m.y, __fmaf_rn(qz, m.z, m.w)));
                const float d2 = fmaxf(__fadd_rn(x, q2), 0.0f);
                u64 cur = ((u64)__float_as_uint(d2) << 32) | (unsigned)sid;
                #pragma unroll
                for (int j = 0; j < KNN; ++j) {
                    const u64 lo = kb[j] < cur ? kb[j] : cur;
                    const u64 hi = kb[j] < cur ? cur : kb[j];
                    kb[j] = lo; cur = hi;
                }
            }
        } else {
            // safety net (>=5.5 sigma): exact full scan, split over 16 lanes
            for (int sid = li; sid < NS; sid += 16) {
                const float4 m = tblf[sid];
                const float x  = __fmaf_rn(qx, m.x,
                                 __fmaf_rn(qy, m.y, __fmaf_rn(qz, m.z, m.w)));
                const float d2 = fmaxf(__fadd_rn(x, q2), 0.0f);
                u64 cur = ((u64)__float_as_uint(d2) << 32) | (unsigned)sid;
                #pragma unroll
                for (int j = 0; j < KNN; ++j) {
                    const u64 lo = kb[j] < cur ? kb[j] : cur;
                    const u64 hi = kb[j] < cur ? cur : kb[j];
                    kb[j] = lo; cur = hi;
                }
            }
        }

        u64 sel = ~0ull;
        #pragma unroll
        for (int r = 0; r < KNN; ++r) {
            u64 v = kb[0];
            #pragma unroll
            for (int m = 1; m <= 8; m <<= 1) {
                const u64 o = __shfl_xor(v, m, 64);   // stays within 16-lane group
                v = o < v ? o : v;
            }
            const bool pop = (kb[0] == v);
            #pragma unroll
            for (int j = 0; j < KNN - 1; ++j) kb[j] = pop ? kb[j+1] : kb[j];
            kb[KNN-1] = pop ? ~0ull : kb[KNN-1];
            if (li == r) sel = v;
        }

        // weights on lanes 0..7 of each subgroup (xor 1,2,4 stays within 0..7)
        const float d2v = __uint_as_float((unsigned)(sel >> 32));
        const int   idx = (int)(unsigned)(sel & 0xFFFFFFFFu);
        const float w   = 1.0f / (sqrtf(d2v) + 1e-8f);
        float ws = w;
        ws += __shfl_xor(ws, 1, 64);
        ws += __shfl_xor(ws, 2, 64);
        ws += __shfl_xor(ws, 4, 64);
        if (li < KNN) {
            s_idx[qr][li] = idx;
            s_w[qr][li]   = w / ws;
        }
    }
    __syncthreads();

    // ---- gather: wave wid -> queries wid*4..+3; 64 lanes x float4 ----
    const float* fb = sf + (size_t)b * NS * FDIM;
    #pragma unroll 1
    for (int jq = 0; jq < QPB / 4; ++jq) {
        const int ql = wid * (QPB / 4) + jq;
        float4 acc = {0.f, 0.f, 0.f, 0.f};
        #pragma unroll
        for (int kk = 0; kk < KNN; ++kk) {
            const int   sid = s_idx[ql][kk];
            const float wk  = s_w[ql][kk];
            const float4 v = ((const float4*)(fb + (size_t)sid * FDIM))[lane];
            acc.x += wk * v.x; acc.y += wk * v.y;
            acc.z += wk * v.z; acc.w += wk * v.w;
        }
        ((float4*)(out + (size_t)(q0 + ql) * FDIM))[lane] = acc;
    }
}

// ================= fallback (round-6 kernel) if workspace too small =================
#define FG    16
#define FQL   2
#define FNT   512
#define FGRP  (FNT / FG)
#define FQPB  (FGRP * FQL)
#define FSCAN (NS / FG)
#define FCAP  16

#define FKEYX(m, qq) __fmaf_rn(fqx[qq], (m).x, \
                     __fmaf_rn(fqy[qq], (m).y, \
                     __fmaf_rn(fqz[qq], (m).z, (m).w)))

__global__ __launch_bounds__(FNT, 4) void idw_fallback(
    const float* __restrict__ qc, const float* __restrict__ sc,
    const float* __restrict__ sf, float* __restrict__ out)
{
    __shared__ float4 s_m[NS];
    __shared__ u64    s_items[FQPB * FCAP];
    __shared__ int    s_cnt[FQPB];
    __shared__ int    s_idx[FQPB * KNN];
    __shared__ float  s_w[FQPB * KNN];

    const int tid = threadIdx.x;
    const int p   = blockIdx.x;
    const int b   = (p >> 1) & 3;
    const int sub = ((p >> 3) << 1) | (p & 1);
    const int q0  = b * NQ + sub * FQPB;

    for (int s = tid; s < NS; s += FNT) {
        const float sx = sc[3*s+0], sy = sc[3*s+1], sz = sc[3*s+2];
        const float s2 = __fmaf_rn(sx, sx, __fmaf_rn(sy, sy, __fmul_rn(sz, sz)));
        s_m[s] = make_float4(-2.0f*sx, -2.0f*sy, -2.0f*sz, s2);
    }
    if (tid < FQPB) s_cnt[tid] = 0;
    __syncthreads();

    const int g = tid >> 4, l = tid & 15;
    float fqx[FQL], fqy[FQL], fqz[FQL], fq2[FQL];
    #pragma unroll
    for (int qq = 0; qq < FQL; ++qq) {
        const float* qp = qc + (size_t)(q0 + g * FQL + qq) * 3;
        fqx[qq] = qp[0]; fqy[qq] = qp[1]; fqz[qq] = qp[2];
        fq2[qq] = __fmaf_rn(fqx[qq], fqx[qq],
                  __fmaf_rn(fqy[qq], fqy[qq], __fmul_rn(fqz[qq], fqz[qq])));
    }

    float kd[FQL][KNN];
    #pragma unroll
    for (int qq = 0; qq < FQL; ++qq)
        #pragma unroll
        for (int j = 0; j < KNN; ++j) kd[qq][j] = 3.4e38f;

    #pragma unroll 2
    for (int t = 0; t < FSCAN; ++t) {
        const float4 m = s_m[t * FG + l];
        #pragma unroll
        for (int qq = 0; qq < FQL; ++qq) {
            const float x = FKEYX(m, qq);
            const float nk0 = fminf(kd[qq][0], x);
            #pragma unroll
            for (int j = KNN - 1; j >= 1; --j)
                kd[qq][j] = med3(kd[qq][j-1], kd[qq][j], x);
            kd[qq][0] = nk0;
        }
    }

    float thr[FQL];
    #pragma unroll
    for (int qq = 0; qq < FQL; ++qq) {
        float thv = 3.4e38f;
        #pragma unroll
        for (int r = 0; r < KNN; ++r) {
            float m = kd[qq][0];
            m = fminf(m, __shfl_xor(m, 1, 64));
            m = fminf(m, __shfl_xor(m, 2, 64));
            m = fminf(m, __shfl_xor(m, 4, 64));
            m = fminf(m, __shfl_xor(m, 8, 64));
            const bool pop = (kd[qq][0] == m);
            #pragma unroll
            for (int j = 0; j < KNN - 1; ++j) kd[qq][j] = pop ? kd[qq][j+1] : kd[qq][j];
            kd[qq][KNN-1] = pop ? 3.4e38f : kd[qq][KNN-1];
            thv = m;
        }
        thr[qq] = thv;
    }

    #pragma unroll 2
    for (int t = 0; t < FSCAN; ++t) {
        const int s = t * FG + l;
        const float4 m = s_m[s];
        #pragma unroll
        for (int qq = 0; qq < FQL; ++qq) {
            const float x = FKEYX(m, qq);
            if (x <= thr[qq]) {
                const float dc = fmaxf(__fadd_rn(x, fq2[qq]), 0.0f);
                const u64 key = ((u64)__float_as_uint(dc) << 32) | (unsigned)s;
                const int qid = g * FQL + qq;
                const int pos = atomicAdd(&s_cnt[qid], 1);
                if (pos < FCAP) s_items[qid * FCAP + pos] = key;
            }
        }
    }
    __syncthreads();

    if (l < FQL) {
        const int qid = g * FQL + l;
        int cnt = s_cnt[qid];
        if (cnt > KNN) {
            cnt = cnt < FCAP ? cnt : FCAP;
            u64 best[KNN];
            #pragma unroll
            for (int j = 0; j < KNN; ++j) best[j] = ~0ull;
            for (int i = 0; i < cnt; ++i) {
                u64 cur = s_items[qid * FCAP + i];
                #pragma unroll
                for (int j = 0; j < KNN; ++j) {
                    const u64 lo = best[j] < cur ? best[j] : cur;
                    const u64 hi = best[j] < cur ? cur : best[j];
                    best[j] = lo; cur = hi;
                }
            }
            #pragma unroll
            for (int j = 0; j < KNN; ++j) s_items[qid * FCAP + j] = best[j];
        }
    }
    __syncthreads();

    {
        const int qq  = l >> 3;
        const int k   = l & 7;
        const int qid = g * FQL + qq;
        const u64 key = s_items[qid * FCAP + k];
        const float d2v = __uint_as_float((unsigned)(key >> 32));
        const int   idx = (int)(unsigned)(key & 0xFFFFFFFFu);
        const float w   = 1.0f / (sqrtf(d2v) + 1e-8f);
        float ws = w;
        ws += __shfl_xor(ws, 1, 64);
        ws += __shfl_xor(ws, 2, 64);
        ws += __shfl_xor(ws, 4, 64);
        s_idx[qid * KNN + k] = idx;
        s_w  [qid * KNN + k] = w / ws;
    }
    __syncthreads();

    const int wave = tid >> 6, lane = tid & 63;
    const float* fb = sf + (size_t)b * NS * FDIM;
    #pragma unroll 1
    for (int j = 0; j < FQPB / 8; ++j) {
        const int ql = wave * (FQPB / 8) + j;
        float4 acc = {0.f, 0.f, 0.f, 0.f};
        #pragma unroll
        for (int kk = 0; kk < KNN; ++kk) {
            const int   sid = s_idx[ql * KNN + kk];
            const float wk  = s_w  [ql * KNN + kk];
            const float4 v = ((const float4*)(fb + (size_t)sid * FDIM))[lane];
            acc.x += wk * v.x; acc.y += wk * v.y;
            acc.z += wk * v.z; acc.w += wk * v.w;
        }
        ((float4*)(out + (size_t)(q0 + ql) * FDIM))[lane] = acc;
    }
}

extern "C" void kernel_launch(void* const* d_in, const int* in_sizes, int n_in,
                              void* d_out, int out_size, void* d_ws, size_t ws_size,
                              hipStream_t stream) {
    const float* qc = (const float*)d_in[0];   // query_coords  (4,8192,3)
    const float* sc = (const float*)d_in[1];   // sensor_coords (4096,3)
    const float* sf = (const float*)d_in[2];   // sensor_features (4,4096,256)
    float* out = (float*)d_out;                // (4,8192,256)

    if (ws_size >= (size_t)WS_NEED) {
        unsigned short* tbl  = (unsigned short*)d_ws;
        float4*         tblf = (float4*)((char*)d_ws + WS_TBLF);
        build_tbl<<<NS / 256, 256, 0, stream>>>(sc, tbl, tblf);
        knn_mfma<<<(BB * NQ) / QPB, 256, 0, stream>>>(qc, sf, tbl, tblf, out);
    } else {
        idw_fallback<<<(BB * NQ) / FQPB, FNT, 0, stream>>>(qc, sc, sf, out);
    }
}